// Round 7
// baseline (395.077 us; speedup 1.0000x reference)
//
#include <hip/hip_runtime.h>
#include <cstdint>

typedef float float4v __attribute__((ext_vector_type(4)));

__device__ __forceinline__ uint32_t mono32(float x) {
    int32_t b = __float_as_int(x);
    return (uint32_t)(b ^ ((b >> 31) | 0x80000000));
}

#define GRID  2048
#define TPB   8          // tiles (of 64 rows) per persistent block

// 4 lanes per row (lane c owns experts 16c..16c+15), 64 rows per tile.
// Persistent blocks, 8 tiles each, register double-buffered: loads for tile
// i+1 are issued before tile i's compute, keeping ~8KB/wave in flight
// continuously. All global traffic perfectly coalesced; no LDS, no barriers.
// Output stores are nontemporal so the write stream doesn't evict the input
// working set from the 256MB L3 (inputs re-hit across timed replays).
__global__ __launch_bounds__(256, 4)
void gumbel_topk_softmax_kernel(const float* __restrict__ gin,
                                const float* __restrict__ gnz,
                                float* __restrict__ gout) {
    const int t = threadIdx.x;
    const int c = t & 3;                       // quarter of row
    const int rl = t >> 2;                     // local row 0..63

    auto tbase = [&](int i) -> size_t {
        return ((size_t)(blockIdx.x + (size_t)i * GRID) * 64 + rl) * 64
             + (size_t)c * 16;
    };

    auto LOAD = [&](size_t b, float4v (&A)[4], float4v (&N)[4]) {
        const float4v* a4 = (const float4v*)(gin + b);
        const float4v* n4 = (const float4v*)(gnz + b);
#pragma unroll
        for (int q = 0; q < 4; ++q) A[q] = a4[q];
#pragma unroll
        for (int q = 0; q < 4; ++q) N[q] = n4[q];
    };

    // ---- R6-proven per-tile body: top-8 select + masked softmax + store ----
    auto BODY = [&](const float4v (&vin)[4], const float4v (&vnz)[4], size_t base) {
        float keys[16];
        float heap[8];
#pragma unroll
        for (int u = 0; u < 8; ++u) heap[u] = -INFINITY;
#pragma unroll
        for (int q = 0; q < 4; ++q)
#pragma unroll
            for (int i = 0; i < 4; ++i) {
                float s = vin[q][i] + vnz[q][i];
                keys[q * 4 + i] = s;
#pragma unroll
                for (int u = 0; u < 8; ++u) {
                    float h = heap[u];
                    heap[u] = fmaxf(h, s);
                    s       = fminf(h, s);
                }
            }

        // merge the 4 lanes' sorted-desc lists -> row top-8
#define CEX(A, B) { float mx = fmaxf(heap[A], heap[B]);                        \
                    float mn = fminf(heap[A], heap[B]);                        \
                    heap[A] = mx; heap[B] = mn; }
#pragma unroll
        for (int m = 1; m <= 2; m <<= 1) {
            float part[8];
#pragma unroll
            for (int u = 0; u < 8; ++u) part[u] = __shfl_xor(heap[7 - u], m);
#pragma unroll
            for (int u = 0; u < 8; ++u) heap[u] = fmaxf(heap[u], part[u]);
            CEX(0, 4) CEX(1, 5) CEX(2, 6) CEX(3, 7)
            CEX(0, 2) CEX(1, 3) CEX(4, 6) CEX(5, 7)
            CEX(0, 1) CEX(2, 3) CEX(4, 5) CEX(6, 7)
        }
#undef CEX

        const float T = heap[7];
        uint32_t m16 = 0u;
        int cnt = 0;
#pragma unroll
        for (int j = 0; j < 16; ++j) {
            bool ge = keys[j] >= T;
            cnt += ge ? 1 : 0;
            m16 |= ge ? (1u << j) : 0u;
        }
        cnt += __shfl_xor(cnt, 1);
        cnt += __shfl_xor(cnt, 2);

        if (cnt != 8) {
            // cold (~3e-5 of rows): f32 tie at rank-8. Exact f64 order via u64
            // key [mono(s) | mono(2Sum residual)>>6 | 63-j]; row re-read from
            // global (L2-hot), redundantly on the row's 4 lanes.
            unsigned long long h8[8];
#pragma unroll
            for (int u = 0; u < 8; ++u) h8[u] = 0ull;
            const float* ar = gin + (base - (size_t)c * 16);
            const float* br = gnz + (base - (size_t)c * 16);
#pragma unroll
            for (int j = 0; j < 64; ++j) {
                float a = ar[j], b = br[j];
                float s  = a + b;
                float ap = s - b;
                float bp = s - ap;
                float res = (a - ap) + (b - bp);
                unsigned long long key = ((unsigned long long)mono32(s) << 32)
                                       | ((unsigned long long)(mono32(res) >> 6) << 6)
                                       | (unsigned long long)(63 - j);
#pragma unroll
                for (int u = 0; u < 8; ++u) {
                    unsigned long long hq = h8[u];
                    unsigned long long mx = key > hq ? key : hq;
                    key   = key > hq ? hq : key;
                    h8[u] = mx;
                }
            }
            unsigned long long mask64 = 0ull;
#pragma unroll
            for (int u = 0; u < 8; ++u)
                mask64 |= 1ull << (63 - (int)(h8[u] & 63ull));
            m16 = (uint32_t)((mask64 >> (c * 16)) & 0xFFFFull);
        }

        // softmax over selected ORIGINAL inputs (no shift: |in| < ~6)
        float4v ev[4];
        float ssum = 0.f;
#pragma unroll
        for (int q = 0; q < 4; ++q)
#pragma unroll
            for (int i = 0; i < 4; ++i) {
                float e = __expf(vin[q][i]) * (float)((m16 >> (q * 4 + i)) & 1u);
                ev[q][i] = e;
                ssum += e;
            }
        ssum += __shfl_xor(ssum, 1);
        ssum += __shfl_xor(ssum, 2);
        const float inv = 1.0f / ssum;

        float4v* o4 = (float4v*)(gout + base);
#pragma unroll
        for (int q = 0; q < 4; ++q) {
            float4v v;
#pragma unroll
            for (int i = 0; i < 4; ++i) v[i] = ev[q][i] * inv;
            __builtin_nontemporal_store(v, o4 + q);
        }
    };

    // ---- software pipeline: named double-buffer halves, unroll by 2 ----
    float4v A0[4], N0[4], A1[4], N1[4];
    LOAD(tbase(0), A0, N0);
#pragma unroll
    for (int p = 0; p < TPB; p += 2) {
        if (p + 1 < TPB) LOAD(tbase(p + 1), A1, N1);   // prefetch (in flight
        BODY(A0, N0, tbase(p));                        //  under this compute)
        if (p + 2 < TPB) LOAD(tbase(p + 2), A0, N0);
        BODY(A1, N1, tbase(p + 1));
    }
}

extern "C" void kernel_launch(void* const* d_in, const int* in_sizes, int n_in,
                              void* d_out, int out_size, void* d_ws, size_t ws_size,
                              hipStream_t stream) {
    const float* gin = (const float*)d_in[0];
    const float* gnz = (const float*)d_in[1];
    float* gout = (float*)d_out;
    // 1,048,576 rows = 16384 tiles of 64 rows = GRID blocks x TPB tiles
    gumbel_topk_softmax_kernel<<<GRID, 256, 0, stream>>>(gin, gnz, gout);
}

// Round 8
// 152.884 us; speedup vs baseline: 2.5842x; 2.5842x over previous
//
#include <hip/hip_runtime.h>
#include <cstdint>

typedef float float4v __attribute__((ext_vector_type(4)));

__device__ __forceinline__ uint32_t mono32(float x) {
    int32_t b = __float_as_int(x);
    return (uint32_t)(b ^ ((b >> 31) | 0x80000000));
}

// async global->LDS, 16B/lane; LDS dest = wave-uniform base + lane*16
__device__ __forceinline__ void gll16(const float* g, float* l) {
    __builtin_amdgcn_global_load_lds((const __attribute__((address_space(1))) void*)g,
                                     (__attribute__((address_space(3))) void*)l, 16, 0, 0);
}

// 256 threads, 64 rows/block, 4 lanes/row. Wave w stages chunks 4w..4w+3
// (= rows 16w..16w+15, R3's proven swizzle: unit p holds row p>>4, quad
// (p&15)^(row&7); each gll instr reads a contiguous permuted 1KB) and consumes
// ONLY its own rows -> no barriers, only the wave's own vmcnt drain.
// Consumption/selection/softmax/store = R6's proven core (normal stores --
// R7 proved nontemporal breaks 16B-store line merging: WRITE 263->607MB).
__global__ __launch_bounds__(256, 4)
void gumbel_topk_softmax_kernel(const float* __restrict__ gin,
                                const float* __restrict__ gnz,
                                float* __restrict__ gout) {
    __shared__ __align__(16) float bufA[64 * 64];   // inputs tile
    __shared__ __align__(16) float bufB[64 * 64];   // noise tile

    const int t    = threadIdx.x;
    const int w    = t >> 6;          // wave 0..3
    const int ln   = t & 63;          // lane
    const int lr   = t >> 2;          // local row 0..63 (wave w: 16w..16w+15)
    const int c    = t & 3;           // quarter of row
    const int row0 = blockIdx.x * 64;

    // ---- stage: 4 chunks per wave per array, contiguous 1KB per instr ----
#pragma unroll
    for (int k2 = 0; k2 < 4; ++k2) {
        const int k = w * 4 + k2;
        const int p = k * 64 + ln;
        const int r = p >> 4;
        const int j = (p & 15) ^ (r & 7);
        const uint32_t gofs = (uint32_t)(row0 + r) * 64u + (uint32_t)j * 4u;
        gll16(gin + gofs, &bufA[k * 256]);
        gll16(gnz + gofs, &bufB[k * 256]);
    }
    asm volatile("s_waitcnt vmcnt(0)" ::: "memory");   // own-wave drain only
    __builtin_amdgcn_sched_barrier(0);                 // rule #18 fence

    // ---- swizzled b128 reads of own row-quarter (8 lanes/bank-group) ----
    float4v vin[4], vnz[4];
#pragma unroll
    for (int q = 0; q < 4; ++q) {
        const int p = lr * 16 + ((c * 4 + q) ^ (lr & 7));
        vin[q] = *(const float4v*)&bufA[p * 4];
        vnz[q] = *(const float4v*)&bufB[p * 4];
    }

    // ---- per-lane bubble top-8 of its 16 z values ----
    float keys[16];
    float heap[8];
#pragma unroll
    for (int u = 0; u < 8; ++u) heap[u] = -INFINITY;
#pragma unroll
    for (int q = 0; q < 4; ++q)
#pragma unroll
        for (int i = 0; i < 4; ++i) {
            float s = vin[q][i] + vnz[q][i];
            keys[q * 4 + i] = s;
#pragma unroll
            for (int u = 0; u < 8; ++u) {
                float h = heap[u];
                heap[u] = fmaxf(h, s);
                s       = fminf(h, s);
            }
        }

    // ---- merge the 4 row-lanes' sorted-desc lists -> row top-8 ----
#define CEX(A, B) { float mx = fmaxf(heap[A], heap[B]);                       \
                    float mn = fminf(heap[A], heap[B]);                       \
                    heap[A] = mx; heap[B] = mn; }
#pragma unroll
    for (int m = 1; m <= 2; m <<= 1) {
        float part[8];
#pragma unroll
        for (int u = 0; u < 8; ++u) part[u] = __shfl_xor(heap[7 - u], m);
#pragma unroll
        for (int u = 0; u < 8; ++u) heap[u] = fmaxf(heap[u], part[u]);
        CEX(0, 4) CEX(1, 5) CEX(2, 6) CEX(3, 7)
        CEX(0, 2) CEX(1, 3) CEX(4, 6) CEX(5, 7)
        CEX(0, 1) CEX(2, 3) CEX(4, 5) CEX(6, 7)
    }
#undef CEX

    // ---- threshold selection + row-wide count ----
    const float T = heap[7];
    uint32_t m16 = 0u;
    int cnt = 0;
#pragma unroll
    for (int j = 0; j < 16; ++j) {
        bool ge = keys[j] >= T;
        cnt += ge ? 1 : 0;
        m16 |= ge ? (1u << j) : 0u;
    }
    cnt += __shfl_xor(cnt, 1);
    cnt += __shfl_xor(cnt, 2);

    if (cnt != 8) {
        // cold (~3e-5 of rows): f32 tie at rank-8. Exact f64 order via u64 key
        // [mono(s) | mono(2Sum residual)>>6 | 63-j]; row re-read from global
        // (L2-hot), redundantly on the row's 4 lanes.
        const size_t row = (size_t)row0 + lr;
        unsigned long long h8[8];
#pragma unroll
        for (int u = 0; u < 8; ++u) h8[u] = 0ull;
        const float* ar = gin + row * 64;
        const float* br = gnz + row * 64;
#pragma unroll
        for (int j = 0; j < 64; ++j) {
            float a = ar[j], b = br[j];
            float s  = a + b;
            float ap = s - b;
            float bp = s - ap;
            float res = (a - ap) + (b - bp);
            unsigned long long key = ((unsigned long long)mono32(s) << 32)
                                   | ((unsigned long long)(mono32(res) >> 6) << 6)
                                   | (unsigned long long)(63 - j);
#pragma unroll
            for (int u = 0; u < 8; ++u) {
                unsigned long long hq = h8[u];
                unsigned long long mx = key > hq ? key : hq;
                key   = key > hq ? hq : key;
                h8[u] = mx;
            }
        }
        unsigned long long mask64 = 0ull;
#pragma unroll
        for (int u = 0; u < 8; ++u) mask64 |= 1ull << (63 - (int)(h8[u] & 63ull));
        m16 = (uint32_t)((mask64 >> (c * 16)) & 0xFFFFull);
    }

    // ---- softmax over selected ORIGINAL inputs (no shift: |in| < ~6) ----
    float4v ev[4];
    float ssum = 0.f;
#pragma unroll
    for (int q = 0; q < 4; ++q)
#pragma unroll
        for (int i = 0; i < 4; ++i) {
            float e = __expf(vin[q][i]) * (float)((m16 >> (q * 4 + i)) & 1u);
            ev[q][i] = e;
            ssum += e;
        }
    ssum += __shfl_xor(ssum, 1);
    ssum += __shfl_xor(ssum, 2);
    const float inv = 1.0f / ssum;

    // ---- direct row stores (normal stores; L2 merges 16B quarters) ----
    float4v* o4 = (float4v*)(gout + ((size_t)row0 + lr) * 64 + (size_t)c * 16);
#pragma unroll
    for (int q = 0; q < 4; ++q) {
        float4v v;
#pragma unroll
        for (int i = 0; i < 4; ++i) v[i] = ev[q][i] * inv;
        o4[q] = v;
    }
}

extern "C" void kernel_launch(void* const* d_in, const int* in_sizes, int n_in,
                              void* d_out, int out_size, void* d_ws, size_t ws_size,
                              hipStream_t stream) {
    const float* gin = (const float*)d_in[0];
    const float* gnz = (const float*)d_in[1];
    float* gout = (float*)d_out;
    const int nrows = in_sizes[0] / 64;        // 1,048,576
    const int grid  = nrows / 64;              // 16384 blocks x 256 threads
    gumbel_topk_softmax_kernel<<<grid, 256, 0, stream>>>(gin, gnz, gout);
}